// Round 3
// baseline (5658.073 us; speedup 1.0000x reference)
//
#include <hip/hip_runtime.h>
#include <hip/hip_bf16.h>
#include <math.h>

#define N_NODES 100000
#define N_EDGES 3200000
#define D 64
#define NUM_RELS 20
#define HID_ATTR 32
#define OUT_ATTR 10

// ---------------- CSR build (counting sort by dst) ----------------

__global__ void deg_count(const int* __restrict__ dst, int* __restrict__ deg) {
    int e = blockIdx.x * 256 + threadIdx.x;
    atomicAdd(&deg[dst[e]], 1);
}

// single block of 1024: exclusive scan of deg[100000] -> off, cur
__global__ void scan_kernel(const int* __restrict__ deg, int* __restrict__ off,
                            int* __restrict__ cur) {
    __shared__ int ps[1024];
    int t = threadIdx.x;
    const int CH = 98;                      // 1024*98 = 100352 >= 100000
    int b0 = t * CH, b1 = min(N_NODES, b0 + CH);
    int s = 0;
    for (int i = b0; i < b1; ++i) s += deg[i];
    ps[t] = s;
    __syncthreads();
    for (int d2 = 1; d2 < 1024; d2 <<= 1) {
        int v = (t >= d2) ? ps[t - d2] : 0;
        __syncthreads();
        ps[t] += v;
        __syncthreads();
    }
    int base = (t == 0) ? 0 : ps[t - 1];
    for (int i = b0; i < b1; ++i) {
        off[i] = base; cur[i] = base; base += deg[i];
    }
    if (t == 0) off[N_NODES] = N_EDGES;
}

// pack (src, rel) into one int: src < 2^17, rel < 2^5
__global__ void scatter_edges(const int* __restrict__ src, const int* __restrict__ dst,
                              const int* __restrict__ etype, int* __restrict__ cur,
                              int* __restrict__ edgedata) {
    int e = blockIdx.x * 256 + threadIdx.x;
    int d = dst[e];
    int pos = atomicAdd(&cur[d], 1);
    edgedata[pos] = src[e] | (etype[e] << 17);
}

// ---------------- phase A: t[q][n][:] = W[r0+q]^T x[n] ----------------
// One wave = one relation, W in 64 VGPRs (lane = out dim o, reg = in dim d).
// x rows read via wave-uniform loads -> scalar loads; pure v_fma inner loop.
__global__ __launch_bounds__(256) void transform_kernel(
    const float* __restrict__ X, const float* __restrict__ W,
    int r0, float* __restrict__ t_out) {
    __shared__ float Wl[D * D];
    int q = blockIdx.y;
    int r = r0 + q;
    const float* Wr = W + (size_t)r * (D * D);
    for (int i = threadIdx.x; i < D * D; i += 256) Wl[i] = Wr[i];
    __syncthreads();
    int wave = threadIdx.x >> 6, lane = threadIdx.x & 63;
    float wv[64];
#pragma unroll
    for (int d2 = 0; d2 < 64; ++d2) wv[d2] = Wl[d2 * 64 + lane];

    int nbase = blockIdx.x * 128 + wave * 32;     // 32 nodes per wave
    for (int g = 0; g < 8; ++g) {
        int n0 = nbase + g * 4;
        int nv = N_NODES - n0;
        if (nv <= 0) break;
        if (nv > 4) nv = 4;
        float acc[4] = {0.f, 0.f, 0.f, 0.f};
#pragma unroll
        for (int kb = 0; kb < 16; ++kb) {
#pragma unroll
            for (int e = 0; e < 4; ++e) {
                if (e < nv) {
                    float4 xq = *(const float4*)(X + (size_t)(n0 + e) * D + kb * 4);
                    acc[e] = fmaf(xq.x, wv[kb * 4 + 0], acc[e]);
                    acc[e] = fmaf(xq.y, wv[kb * 4 + 1], acc[e]);
                    acc[e] = fmaf(xq.z, wv[kb * 4 + 2], acc[e]);
                    acc[e] = fmaf(xq.w, wv[kb * 4 + 3], acc[e]);
                }
            }
        }
        for (int e = 0; e < nv; ++e)
            t_out[((size_t)q * N_NODES + (n0 + e)) * D + lane] = acc[e];
    }
}

// ---------------- phase B: agg[v] (+)= sum_{e->v, rel in chunk} t[rel-r0][src] ----
// One wave per dst node; no atomics (deterministic owner).
__global__ __launch_bounds__(256) void gather_agg(
    const float* __restrict__ t, const int* __restrict__ edgedata,
    const int* __restrict__ off, float* __restrict__ agg,
    int r0, int rpc, int accum, int do_relu) {
    int gw = (blockIdx.x * 256 + threadIdx.x) >> 6;
    int nw = (gridDim.x * 256) >> 6;
    int lane = threadIdx.x & 63;
    for (int v = gw; v < N_NODES; v += nw) {
        int beg = off[v], end = off[v + 1];
        float a0 = 0.f, a1 = 0.f;
        int i = beg;
        for (; i + 1 < end; i += 2) {
            int ew0 = edgedata[i], ew1 = edgedata[i + 1];
            unsigned q0 = (unsigned)(ew0 >> 17) - (unsigned)r0;
            unsigned q1 = (unsigned)(ew1 >> 17) - (unsigned)r0;
            if (q0 < (unsigned)rpc)
                a0 += t[((size_t)q0 * N_NODES + (ew0 & 0x1FFFF)) * D + lane];
            if (q1 < (unsigned)rpc)
                a1 += t[((size_t)q1 * N_NODES + (ew1 & 0x1FFFF)) * D + lane];
        }
        if (i < end) {
            int ew0 = edgedata[i];
            unsigned q0 = (unsigned)(ew0 >> 17) - (unsigned)r0;
            if (q0 < (unsigned)rpc)
                a0 += t[((size_t)q0 * N_NODES + (ew0 & 0x1FFFF)) * D + lane];
        }
        float res = a0 + a1;
        if (accum) res += agg[(size_t)v * D + lane];
        if (do_relu) res = fmaxf(res, 0.f);
        agg[(size_t)v * D + lane] = res;
    }
}

// ---------------- readout ----------------

__global__ void colsum_kernel(const float* __restrict__ h2,
                              float* __restrict__ g, int n) {
    __shared__ float s[256];
    int tid = threadIdx.x;
    int col = tid & 63;
    int rowgrp = (blockIdx.x * blockDim.x + tid) >> 6;
    int nrowgrp = (gridDim.x * blockDim.x) >> 6;
    float acc = 0.0f;
    for (int row = rowgrp; row < n; row += nrowgrp)
        acc += h2[(size_t)row * D + col];
    s[tid] = acc;
    __syncthreads();
    if (tid < 64) {
        acc = s[tid] + s[tid + 64] + s[tid + 128] + s[tid + 192];
        atomicAdd(&g[col], acc);
    }
}

__global__ void mlp_kernel(const float* __restrict__ g,
                           const float* __restrict__ A1w,
                           const float* __restrict__ A1b,
                           const float* __restrict__ A2w,
                           const float* __restrict__ A2b,
                           float* __restrict__ out, float invN) {
    __shared__ float a1[HID_ATTR];
    int t = threadIdx.x;
    if (t < HID_ATTR) {
        float acc = A1b[t];
#pragma unroll
        for (int d2 = 0; d2 < D; ++d2)
            acc = fmaf(g[d2] * invN, A1w[d2 * HID_ATTR + t], acc);
        a1[t] = fmaxf(acc, 0.0f);
    }
    __syncthreads();
    if (t < OUT_ATTR) {
        float acc = A2b[t];
#pragma unroll
        for (int j = 0; j < HID_ATTR; ++j)
            acc = fmaf(a1[j], A2w[j * OUT_ATTR + t], acc);
        out[t] = 1.0f / (1.0f + expf(-acc));
    }
}

// ---------------- launch ----------------

extern "C" void kernel_launch(void* const* d_in, const int* in_sizes, int n_in,
                              void* d_out, int out_size, void* d_ws, size_t ws_size,
                              hipStream_t stream) {
    const float* h   = (const float*)d_in[0];
    const int* src   = (const int*)d_in[1];
    const int* dst   = (const int*)d_in[2];
    const int* etype = (const int*)d_in[3];
    const float* W1  = (const float*)d_in[4];
    const float* W2  = (const float*)d_in[5];
    const float* A1w = (const float*)d_in[6];
    const float* A1b = (const float*)d_in[7];
    const float* A2w = (const float*)d_in[8];
    const float* A2b = (const float*)d_in[9];

    float* out_h2 = (float*)d_out;                  // [N_NODES, D]
    float* out_a  = out_h2 + (size_t)N_NODES * D;   // [10]

    // workspace layout (4B elems)
    float* agg1   = (float*)d_ws;                   // 6,400,000
    float* gsum   = agg1 + (size_t)N_NODES * D;     // 64
    int* deg      = (int*)(gsum + 64);              // 100,000
    int* off      = deg + N_NODES;                  // 100,001
    int* cur      = off + N_NODES + 1;              // 100,000
    int* edgedata = cur + N_NODES;                  // 3,200,000
    const size_t FIXED = 9900080;                   // padded elem count
    float* tbuf   = (float*)((char*)d_ws + FIXED * 4);

    // pick relations-per-chunk so t-chunk fits in workspace
    int RPC = 1;
    if (ws_size >= (FIXED + (size_t)4 * N_NODES * D) * 4) RPC = 4;
    else if (ws_size >= (FIXED + (size_t)2 * N_NODES * D) * 4) RPC = 2;
    int NC = NUM_RELS / RPC;

    hipMemsetAsync(deg, 0, N_NODES * sizeof(int), stream);
    hipMemsetAsync(gsum, 0, 64 * sizeof(float), stream);

    // CSR by dst
    deg_count<<<N_EDGES / 256, 256, 0, stream>>>(dst, deg);
    scan_kernel<<<1, 1024, 0, stream>>>(deg, off, cur);
    scatter_edges<<<N_EDGES / 256, 256, 0, stream>>>(src, dst, etype, cur, edgedata);

    dim3 tgrid(782, RPC);    // 782*128 = 100096 nodes

    // layer 1: agg1 = relu(segment_sum(W1[r]^T h[src] -> dst))
    for (int c = 0; c < NC; ++c) {
        transform_kernel<<<tgrid, 256, 0, stream>>>(h, W1, c * RPC, tbuf);
        gather_agg<<<4096, 256, 0, stream>>>(tbuf, edgedata, off, agg1,
                                             c * RPC, RPC, c > 0, c == NC - 1);
    }
    // layer 2: out_h2 = segment_sum(W2[r]^T agg1[src] -> dst)
    for (int c = 0; c < NC; ++c) {
        transform_kernel<<<tgrid, 256, 0, stream>>>(agg1, W2, c * RPC, tbuf);
        gather_agg<<<4096, 256, 0, stream>>>(tbuf, edgedata, off, out_h2,
                                             c * RPC, RPC, c > 0, 0);
    }

    // readout
    colsum_kernel<<<512, 256, 0, stream>>>(out_h2, gsum, N_NODES);
    mlp_kernel<<<1, 64, 0, stream>>>(gsum, A1w, A1b, A2w, A2b,
                                     out_a, 1.0f / (float)N_NODES);
}

// Round 4
// 1565.608 us; speedup vs baseline: 3.6140x; 3.6140x over previous
//
#include <hip/hip_runtime.h>
#include <hip/hip_bf16.h>
#include <math.h>

#define N_NODES 100000
#define N_EDGES 3200000
#define D 64
#define NUM_RELS 20
#define HID_ATTR 32
#define OUT_ATTR 10

typedef __attribute__((ext_vector_type(8))) short bf16x8;
typedef __attribute__((ext_vector_type(4))) float f32x4;

static __device__ __forceinline__ unsigned short f2bf(float x) {
    unsigned u = __builtin_bit_cast(unsigned, x);
    unsigned r = (u + 0x7FFFu + ((u >> 16) & 1u)) >> 16;
    return (unsigned short)r;
}
static __device__ __forceinline__ float bf2f(unsigned short b) {
    return __builtin_bit_cast(float, (unsigned)b << 16);
}

// ---------------- CSR build (counting sort by dst) ----------------

__global__ void deg_count(const int* __restrict__ dst, int* __restrict__ deg) {
    int e = blockIdx.x * 256 + threadIdx.x;
    atomicAdd(&deg[dst[e]], 1);
}

__global__ void scan_kernel(const int* __restrict__ deg, int* __restrict__ off,
                            int* __restrict__ cur) {
    __shared__ int ps[1024];
    int t = threadIdx.x;
    const int CH = 98;
    int b0 = t * CH, b1 = min(N_NODES, b0 + CH);
    int s = 0;
    for (int i = b0; i < b1; ++i) s += deg[i];
    ps[t] = s;
    __syncthreads();
    for (int d2 = 1; d2 < 1024; d2 <<= 1) {
        int v = (t >= d2) ? ps[t - d2] : 0;
        __syncthreads();
        ps[t] += v;
        __syncthreads();
    }
    int base = (t == 0) ? 0 : ps[t - 1];
    for (int i = b0; i < b1; ++i) {
        off[i] = base; cur[i] = base; base += deg[i];
    }
    if (t == 0) off[N_NODES] = N_EDGES;
}

// pack (src, rel): src < 2^17, rel < 2^5
__global__ void scatter_edges(const int* __restrict__ src, const int* __restrict__ dst,
                              const int* __restrict__ etype, int* __restrict__ cur,
                              int* __restrict__ edgedata) {
    int e = blockIdx.x * 256 + threadIdx.x;
    int d = dst[e];
    int pos = atomicAdd(&cur[d], 1);
    edgedata[pos] = src[e] | (etype[e] << 17);
}

// ---------------- dtype conversions ----------------

// float -> bf16 (optionally relu first); n4 = count of float4 groups
__global__ void f2b_kernel(const float* __restrict__ in, unsigned short* __restrict__ out,
                           int n4, int relu) {
    int i = blockIdx.x * 256 + threadIdx.x;
    if (i >= n4) return;
    float4 v = ((const float4*)in)[i];
    if (relu) {
        v.x = fmaxf(v.x, 0.f); v.y = fmaxf(v.y, 0.f);
        v.z = fmaxf(v.z, 0.f); v.w = fmaxf(v.w, 0.f);
    }
    ushort4 o;
    o.x = f2bf(v.x); o.y = f2bf(v.y); o.z = f2bf(v.z); o.w = f2bf(v.w);
    ((ushort4*)out)[i] = o;
}

// W[r][d][o] fp32 -> Wb[r][o][d] bf16 (transposed for MFMA B-frag loads)
__global__ void wconv_kernel(const float* __restrict__ W, unsigned short* __restrict__ Wb) {
    int r = blockIdx.x;
    for (int i = threadIdx.x; i < D * D; i += 256) {
        int d2 = i >> 6, o = i & 63;
        Wb[(size_t)r * (D * D) + o * D + d2] = f2bf(W[(size_t)r * (D * D) + d2 * D + o]);
    }
}

// ---------------- phase A: t[q][n][:] = Xb[n] @ W[r0+q]  (bf16 MFMA) ----------------
// One wave = one 16-node tile x one relation. K=64 via 2x mfma_16x16x32 per n-tile.
// A-frag: A[m=lane&15][k=(lane>>4)*8+j]  (verified layout)
// B-frag: B[k=(lane>>4)*8+j][n=lane&15]  -> contiguous in Wb[r][o][d]
// C/D:    col=lane&15, row=(lane>>4)*4+reg (verified layout)
__global__ __launch_bounds__(256) void transform_mfma(
    const unsigned short* __restrict__ Xb, const unsigned short* __restrict__ Wb,
    int r0, unsigned short* __restrict__ t_out) {
    int wave = threadIdx.x >> 6, lane = threadIdx.x & 63;
    int tile = blockIdx.x * 4 + wave;
    if (tile >= N_NODES / 16) return;
    int q = blockIdx.y;
    const unsigned short* Wr = Wb + ((size_t)(r0 + q) << 12);
    int n0 = tile * 16;
    int lrow = lane & 15, lhi = lane >> 4;

    const unsigned short* xrow = Xb + (size_t)(n0 + lrow) * D + lhi * 8;
    bf16x8 a0 = *(const bf16x8*)(xrow);
    bf16x8 a1 = *(const bf16x8*)(xrow + 32);

    unsigned short* tq = t_out + (size_t)q * ((size_t)N_NODES * D);
    f32x4 acc[4];
#pragma unroll
    for (int ot = 0; ot < 4; ++ot) {
        const unsigned short* wrow = Wr + (size_t)(ot * 16 + lrow) * D + lhi * 8;
        bf16x8 b0 = *(const bf16x8*)(wrow);
        bf16x8 b1 = *(const bf16x8*)(wrow + 32);
        f32x4 c = {0.f, 0.f, 0.f, 0.f};
        c = __builtin_amdgcn_mfma_f32_16x16x32_bf16(a0, b0, c, 0, 0, 0);
        c = __builtin_amdgcn_mfma_f32_16x16x32_bf16(a1, b1, c, 0, 0, 0);
        acc[ot] = c;
    }
#pragma unroll
    for (int ot = 0; ot < 4; ++ot)
#pragma unroll
        for (int reg = 0; reg < 4; ++reg) {
            int node = n0 + lhi * 4 + reg;
            tq[(size_t)node * D + ot * 16 + lrow] = f2bf(acc[ot][reg]);
        }
}

// ---------------- phase B: agg[v] (+)= sum_{e->v, rel in chunk} t[rel-r0][src] ----
// One wave per dst node, no atomics; 4-edge unroll for load ILP; bf16 t reads.
__global__ __launch_bounds__(256) void gather_agg(
    const unsigned short* __restrict__ t, const int* __restrict__ edgedata,
    const int* __restrict__ off, float* __restrict__ agg,
    int r0, int rpc, int accum) {
    int gw = (blockIdx.x * 256 + threadIdx.x) >> 6;
    int nw = (gridDim.x * 256) >> 6;
    int lane = threadIdx.x & 63;
    for (int v = gw; v < N_NODES; v += nw) {
        int beg = off[v], end = off[v + 1];
        float a0 = 0.f, a1 = 0.f, a2 = 0.f, a3 = 0.f;
        int i = beg;
        for (; i + 3 < end; i += 4) {
            int e0 = edgedata[i], e1 = edgedata[i + 1];
            int e2 = edgedata[i + 2], e3 = edgedata[i + 3];
            unsigned q0 = (unsigned)(e0 >> 17) - (unsigned)r0;
            unsigned q1 = (unsigned)(e1 >> 17) - (unsigned)r0;
            unsigned q2 = (unsigned)(e2 >> 17) - (unsigned)r0;
            unsigned q3 = (unsigned)(e3 >> 17) - (unsigned)r0;
            if (q0 < (unsigned)rpc)
                a0 += bf2f(t[((size_t)q0 * N_NODES + (e0 & 0x1FFFF)) * D + lane]);
            if (q1 < (unsigned)rpc)
                a1 += bf2f(t[((size_t)q1 * N_NODES + (e1 & 0x1FFFF)) * D + lane]);
            if (q2 < (unsigned)rpc)
                a2 += bf2f(t[((size_t)q2 * N_NODES + (e2 & 0x1FFFF)) * D + lane]);
            if (q3 < (unsigned)rpc)
                a3 += bf2f(t[((size_t)q3 * N_NODES + (e3 & 0x1FFFF)) * D + lane]);
        }
        for (; i < end; ++i) {
            int e0 = edgedata[i];
            unsigned q0 = (unsigned)(e0 >> 17) - (unsigned)r0;
            if (q0 < (unsigned)rpc)
                a0 += bf2f(t[((size_t)q0 * N_NODES + (e0 & 0x1FFFF)) * D + lane]);
        }
        float res = (a0 + a1) + (a2 + a3);
        if (accum) res += agg[(size_t)v * D + lane];
        agg[(size_t)v * D + lane] = res;
    }
}

// ---------------- readout ----------------

__global__ void colsum_kernel(const float* __restrict__ h2,
                              float* __restrict__ g, int n) {
    __shared__ float s[256];
    int tid = threadIdx.x;
    int col = tid & 63;
    int rowgrp = (blockIdx.x * blockDim.x + tid) >> 6;
    int nrowgrp = (gridDim.x * blockDim.x) >> 6;
    float acc = 0.0f;
    for (int row = rowgrp; row < n; row += nrowgrp)
        acc += h2[(size_t)row * D + col];
    s[tid] = acc;
    __syncthreads();
    if (tid < 64) {
        acc = s[tid] + s[tid + 64] + s[tid + 128] + s[tid + 192];
        atomicAdd(&g[col], acc);
    }
}

__global__ void mlp_kernel(const float* __restrict__ g,
                           const float* __restrict__ A1w,
                           const float* __restrict__ A1b,
                           const float* __restrict__ A2w,
                           const float* __restrict__ A2b,
                           float* __restrict__ out, float invN) {
    __shared__ float a1[HID_ATTR];
    int t = threadIdx.x;
    if (t < HID_ATTR) {
        float acc = A1b[t];
#pragma unroll
        for (int d2 = 0; d2 < D; ++d2)
            acc = fmaf(g[d2] * invN, A1w[d2 * HID_ATTR + t], acc);
        a1[t] = fmaxf(acc, 0.0f);
    }
    __syncthreads();
    if (t < OUT_ATTR) {
        float acc = A2b[t];
#pragma unroll
        for (int j = 0; j < HID_ATTR; ++j)
            acc = fmaf(a1[j], A2w[j * OUT_ATTR + t], acc);
        out[t] = 1.0f / (1.0f + expf(-acc));
    }
}

// ---------------- launch ----------------

extern "C" void kernel_launch(void* const* d_in, const int* in_sizes, int n_in,
                              void* d_out, int out_size, void* d_ws, size_t ws_size,
                              hipStream_t stream) {
    const float* h   = (const float*)d_in[0];
    const int* src   = (const int*)d_in[1];
    const int* dst   = (const int*)d_in[2];
    const int* etype = (const int*)d_in[3];
    const float* W1  = (const float*)d_in[4];
    const float* W2  = (const float*)d_in[5];
    const float* A1w = (const float*)d_in[6];
    const float* A1b = (const float*)d_in[7];
    const float* A2w = (const float*)d_in[8];
    const float* A2b = (const float*)d_in[9];

    float* out_h2 = (float*)d_out;
    float* out_a  = out_h2 + (size_t)N_NODES * D;

    // workspace layout
    float* agg1   = (float*)d_ws;                         // 6,400,000 f32
    float* gsum   = agg1 + (size_t)N_NODES * D;           // 64
    int* deg      = (int*)(gsum + 64);                    // 100,000
    int* off      = deg + N_NODES;                        // 100,004 (padded for 16B align)
    int* cur      = off + (N_NODES + 4);                  // 100,000
    int* edgedata = cur + N_NODES;                        // 3,200,000
    unsigned short* xb  = (unsigned short*)(edgedata + N_EDGES);  // 6,400,000 u16
    unsigned short* w1b = xb + (size_t)N_NODES * D;       // 81,920 u16
    unsigned short* w2b = w1b + NUM_RELS * D * D;         // 81,920 u16
    unsigned short* tbuf = w2b + NUM_RELS * D * D;        // RPC * 6,400,000 u16

    const size_t fixedB = (size_t)((char*)tbuf - (char*)d_ws);
    const size_t chunkB = (size_t)N_NODES * D * 2;        // 12.8 MB per relation
    int RPC = 1;
    if (ws_size >= fixedB + 20 * chunkB) RPC = 20;
    else if (ws_size >= fixedB + 10 * chunkB) RPC = 10;
    else if (ws_size >= fixedB + 5 * chunkB) RPC = 5;
    else if (ws_size >= fixedB + 2 * chunkB) RPC = 2;
    int NC = NUM_RELS / RPC;

    hipMemsetAsync(deg, 0, N_NODES * sizeof(int), stream);
    hipMemsetAsync(gsum, 0, 64 * sizeof(float), stream);

    // CSR by dst + weight conversion
    deg_count<<<N_EDGES / 256, 256, 0, stream>>>(dst, deg);
    scan_kernel<<<1, 1024, 0, stream>>>(deg, off, cur);
    scatter_edges<<<N_EDGES / 256, 256, 0, stream>>>(src, dst, etype, cur, edgedata);
    wconv_kernel<<<NUM_RELS, 256, 0, stream>>>(W1, w1b);
    wconv_kernel<<<NUM_RELS, 256, 0, stream>>>(W2, w2b);

    const int N4 = N_NODES * D / 4;                       // 1.6M float4 groups
    dim3 tgrid((N_NODES / 16 + 3) / 4, RPC);              // 1563 x RPC

    // layer 1
    f2b_kernel<<<(N4 + 255) / 256, 256, 0, stream>>>(h, xb, N4, 0);
    for (int c = 0; c < NC; ++c) {
        transform_mfma<<<tgrid, 256, 0, stream>>>(xb, w1b, c * RPC, tbuf);
        gather_agg<<<4096, 256, 0, stream>>>(tbuf, edgedata, off, agg1,
                                             c * RPC, RPC, c > 0);
    }
    // layer 2 (relu folded into conversion)
    f2b_kernel<<<(N4 + 255) / 256, 256, 0, stream>>>(agg1, xb, N4, 1);
    for (int c = 0; c < NC; ++c) {
        transform_mfma<<<tgrid, 256, 0, stream>>>(xb, w2b, c * RPC, tbuf);
        gather_agg<<<4096, 256, 0, stream>>>(tbuf, edgedata, off, out_h2,
                                             c * RPC, RPC, c > 0);
    }

    // readout
    colsum_kernel<<<512, 256, 0, stream>>>(out_h2, gsum, N_NODES);
    mlp_kernel<<<1, 64, 0, stream>>>(gsum, A1w, A1b, A2w, A2b,
                                     out_a, 1.0f / (float)N_NODES);
}

// Round 5
// 1346.996 us; speedup vs baseline: 4.2005x; 1.1623x over previous
//
#include <hip/hip_runtime.h>
#include <hip/hip_bf16.h>
#include <math.h>

#define N_NODES 100000
#define N_EDGES 3200000
#define D 64
#define NUM_RELS 20
#define HID_ATTR 32
#define OUT_ATTR 10
#define SCAN_B 391              // ceil(N_NODES / 256)

typedef __attribute__((ext_vector_type(8))) short bf16x8;
typedef __attribute__((ext_vector_type(4))) float f32x4;

static __device__ __forceinline__ unsigned short f2bf(float x) {
    unsigned u = __builtin_bit_cast(unsigned, x);
    unsigned r = (u + 0x7FFFu + ((u >> 16) & 1u)) >> 16;
    return (unsigned short)r;
}
static __device__ __forceinline__ float bf2f(unsigned short b) {
    return __builtin_bit_cast(float, (unsigned)b << 16);
}

// ---------------- CSR build (counting sort by dst) ----------------

__global__ void deg_count(const int* __restrict__ dst, int* __restrict__ deg) {
    int e = blockIdx.x * 256 + threadIdx.x;
    atomicAdd(&deg[dst[e]], 1);
}

// multi-block exclusive scan of deg[N_NODES] -> off, cur
__global__ void scan_bsum(const int* __restrict__ deg, int* __restrict__ bsum) {
    __shared__ int s[256];
    int t = threadIdx.x, i = blockIdx.x * 256 + t;
    s[t] = (i < N_NODES) ? deg[i] : 0;
    __syncthreads();
    for (int d2 = 128; d2 > 0; d2 >>= 1) {
        if (t < d2) s[t] += s[t + d2];
        __syncthreads();
    }
    if (t == 0) bsum[blockIdx.x] = s[0];
}

__global__ void scan_bbase(const int* __restrict__ bsum, int* __restrict__ bbase,
                           int* __restrict__ off) {
    __shared__ int s[512];
    int t = threadIdx.x;
    int v = (t < SCAN_B) ? bsum[t] : 0;
    s[t] = v;
    __syncthreads();
    for (int d2 = 1; d2 < 512; d2 <<= 1) {
        int x = (t >= d2) ? s[t - d2] : 0;
        __syncthreads();
        s[t] += x;
        __syncthreads();
    }
    if (t < SCAN_B) bbase[t] = s[t] - v;      // exclusive
    if (t == 0) off[N_NODES] = N_EDGES;
}

__global__ void scan_final(const int* __restrict__ deg, const int* __restrict__ bbase,
                           int* __restrict__ off, int* __restrict__ cur) {
    __shared__ int s[256];
    int t = threadIdx.x, i = blockIdx.x * 256 + t;
    int v = (i < N_NODES) ? deg[i] : 0;
    s[t] = v;
    __syncthreads();
    for (int d2 = 1; d2 < 256; d2 <<= 1) {
        int x = (t >= d2) ? s[t - d2] : 0;
        __syncthreads();
        s[t] += x;
        __syncthreads();
    }
    if (i < N_NODES) {
        int e = bbase[blockIdx.x] + s[t] - v;  // exclusive prefix
        off[i] = e; cur[i] = e;
    }
}

// pack (src, rel): src < 2^17, rel < 2^5
__global__ void scatter_edges(const int* __restrict__ src, const int* __restrict__ dst,
                              const int* __restrict__ etype, int* __restrict__ cur,
                              int* __restrict__ edgedata) {
    int e = blockIdx.x * 256 + threadIdx.x;
    int d = dst[e];
    int pos = atomicAdd(&cur[d], 1);
    edgedata[pos] = src[e] | (etype[e] << 17);
}

// ---------------- dtype conversions ----------------

__global__ void f2b_kernel(const float* __restrict__ in, unsigned short* __restrict__ out,
                           int n4, int relu) {
    int i = blockIdx.x * 256 + threadIdx.x;
    if (i >= n4) return;
    float4 v = ((const float4*)in)[i];
    if (relu) {
        v.x = fmaxf(v.x, 0.f); v.y = fmaxf(v.y, 0.f);
        v.z = fmaxf(v.z, 0.f); v.w = fmaxf(v.w, 0.f);
    }
    ushort4 o;
    o.x = f2bf(v.x); o.y = f2bf(v.y); o.z = f2bf(v.z); o.w = f2bf(v.w);
    ((ushort4*)out)[i] = o;
}

// W[r][d][o] fp32 -> Wb[r][o][d] bf16 (transposed for MFMA B-frag loads)
__global__ void wconv_kernel(const float* __restrict__ W, unsigned short* __restrict__ Wb) {
    int r = blockIdx.x;
    for (int i = threadIdx.x; i < D * D; i += 256) {
        int d2 = i >> 6, o = i & 63;
        Wb[(size_t)r * (D * D) + o * D + d2] = f2bf(W[(size_t)r * (D * D) + d2 * D + o]);
    }
}

// ---------------- phase A: t[q][n][:] = Xb[n] @ W[r0+q]  (bf16 MFMA) ----------------
__global__ __launch_bounds__(256) void transform_mfma(
    const unsigned short* __restrict__ Xb, const unsigned short* __restrict__ Wb,
    int r0, unsigned short* __restrict__ t_out) {
    int wave = threadIdx.x >> 6, lane = threadIdx.x & 63;
    int tile = blockIdx.x * 4 + wave;
    if (tile >= N_NODES / 16) return;
    int q = blockIdx.y;
    const unsigned short* Wr = Wb + ((size_t)(r0 + q) << 12);
    int n0 = tile * 16;
    int lrow = lane & 15, lhi = lane >> 4;

    const unsigned short* xrow = Xb + (size_t)(n0 + lrow) * D + lhi * 8;
    bf16x8 a0 = *(const bf16x8*)(xrow);
    bf16x8 a1 = *(const bf16x8*)(xrow + 32);

    unsigned short* tq = t_out + (size_t)q * ((size_t)N_NODES * D);
    f32x4 acc[4];
#pragma unroll
    for (int ot = 0; ot < 4; ++ot) {
        const unsigned short* wrow = Wr + (size_t)(ot * 16 + lrow) * D + lhi * 8;
        bf16x8 b0 = *(const bf16x8*)(wrow);
        bf16x8 b1 = *(const bf16x8*)(wrow + 32);
        f32x4 c = {0.f, 0.f, 0.f, 0.f};
        c = __builtin_amdgcn_mfma_f32_16x16x32_bf16(a0, b0, c, 0, 0, 0);
        c = __builtin_amdgcn_mfma_f32_16x16x32_bf16(a1, b1, c, 0, 0, 0);
        acc[ot] = c;
    }
#pragma unroll
    for (int ot = 0; ot < 4; ++ot)
#pragma unroll
        for (int reg = 0; reg < 4; ++reg) {
            int node = n0 + lhi * 4 + reg;
            tq[(size_t)node * D + ot * 16 + lrow] = f2bf(acc[ot][reg]);
        }
}

// ---------------- phase B: per-dst gather of t rows, no atomics ----------------
// mode 0: write aggf fp32 (accum optional)
// mode 1: final layer-1 pass: (+ aggf if accum), relu, write outb bf16 only
// mode 2: write aggf fp32 (this IS out_h2)
__global__ __launch_bounds__(256) void gather_agg(
    const unsigned short* __restrict__ t, const int* __restrict__ edgedata,
    const int* __restrict__ off, float* __restrict__ aggf,
    unsigned short* __restrict__ outb,
    int r0, int rpc, int accum, int mode) {
    int gw = (blockIdx.x * 256 + threadIdx.x) >> 6;
    int nw = (gridDim.x * 256) >> 6;
    int lane = threadIdx.x & 63;
    for (int v = gw; v < N_NODES; v += nw) {
        int beg = off[v], end = off[v + 1];
        float a0 = 0.f, a1 = 0.f, a2 = 0.f, a3 = 0.f;
        int i = beg;
        for (; i + 3 < end; i += 4) {
            int e0 = edgedata[i], e1 = edgedata[i + 1];
            int e2 = edgedata[i + 2], e3 = edgedata[i + 3];
            unsigned q0 = (unsigned)(e0 >> 17) - (unsigned)r0;
            unsigned q1 = (unsigned)(e1 >> 17) - (unsigned)r0;
            unsigned q2 = (unsigned)(e2 >> 17) - (unsigned)r0;
            unsigned q3 = (unsigned)(e3 >> 17) - (unsigned)r0;
            if (q0 < (unsigned)rpc)
                a0 += bf2f(t[((size_t)q0 * N_NODES + (e0 & 0x1FFFF)) * D + lane]);
            if (q1 < (unsigned)rpc)
                a1 += bf2f(t[((size_t)q1 * N_NODES + (e1 & 0x1FFFF)) * D + lane]);
            if (q2 < (unsigned)rpc)
                a2 += bf2f(t[((size_t)q2 * N_NODES + (e2 & 0x1FFFF)) * D + lane]);
            if (q3 < (unsigned)rpc)
                a3 += bf2f(t[((size_t)q3 * N_NODES + (e3 & 0x1FFFF)) * D + lane]);
        }
        for (; i < end; ++i) {
            int e0 = edgedata[i];
            unsigned q0 = (unsigned)(e0 >> 17) - (unsigned)r0;
            if (q0 < (unsigned)rpc)
                a0 += bf2f(t[((size_t)q0 * N_NODES + (e0 & 0x1FFFF)) * D + lane]);
        }
        float res = (a0 + a1) + (a2 + a3);
        size_t idx = (size_t)v * D + lane;
        if (accum) res += aggf[idx];
        if (mode == 1) {
            outb[idx] = f2bf(fmaxf(res, 0.f));
        } else {
            aggf[idx] = res;
        }
    }
}

// ---------------- readout ----------------

__global__ void colsum_kernel(const float* __restrict__ h2,
                              float* __restrict__ g, int n) {
    __shared__ float s[256];
    int tid = threadIdx.x;
    int col = tid & 63;
    int rowgrp = (blockIdx.x * blockDim.x + tid) >> 6;
    int nrowgrp = (gridDim.x * blockDim.x) >> 6;
    float acc = 0.0f;
    for (int row = rowgrp; row < n; row += nrowgrp)
        acc += h2[(size_t)row * D + col];
    s[tid] = acc;
    __syncthreads();
    if (tid < 64) {
        acc = s[tid] + s[tid + 64] + s[tid + 128] + s[tid + 192];
        atomicAdd(&g[col], acc);
    }
}

__global__ void mlp_kernel(const float* __restrict__ g,
                           const float* __restrict__ A1w,
                           const float* __restrict__ A1b,
                           const float* __restrict__ A2w,
                           const float* __restrict__ A2b,
                           float* __restrict__ out, float invN) {
    __shared__ float a1[HID_ATTR];
    int t = threadIdx.x;
    if (t < HID_ATTR) {
        float acc = A1b[t];
#pragma unroll
        for (int d2 = 0; d2 < D; ++d2)
            acc = fmaf(g[d2] * invN, A1w[d2 * HID_ATTR + t], acc);
        a1[t] = fmaxf(acc, 0.0f);
    }
    __syncthreads();
    if (t < OUT_ATTR) {
        float acc = A2b[t];
#pragma unroll
        for (int j = 0; j < HID_ATTR; ++j)
            acc = fmaf(a1[j], A2w[j * OUT_ATTR + t], acc);
        out[t] = 1.0f / (1.0f + expf(-acc));
    }
}

// ---------------- launch ----------------

extern "C" void kernel_launch(void* const* d_in, const int* in_sizes, int n_in,
                              void* d_out, int out_size, void* d_ws, size_t ws_size,
                              hipStream_t stream) {
    const float* h   = (const float*)d_in[0];
    const int* src   = (const int*)d_in[1];
    const int* dst   = (const int*)d_in[2];
    const int* etype = (const int*)d_in[3];
    const float* W1  = (const float*)d_in[4];
    const float* W2  = (const float*)d_in[5];
    const float* A1w = (const float*)d_in[6];
    const float* A1b = (const float*)d_in[7];
    const float* A2w = (const float*)d_in[8];
    const float* A2b = (const float*)d_in[9];

    float* out_h2 = (float*)d_out;
    float* out_a  = out_h2 + (size_t)N_NODES * D;

    // workspace layout
    float* agg1   = (float*)d_ws;                         // 6,400,000 f32
    float* gsum   = agg1 + (size_t)N_NODES * D;           // 64
    int* deg      = (int*)(gsum + 64);                    // 100,000
    int* off      = deg + N_NODES;                        // 100,004
    int* cur      = off + (N_NODES + 4);                  // 100,000
    int* bsum     = cur + N_NODES;                        // 512
    int* bbase    = bsum + 512;                           // 512
    int* edgedata = bbase + 512;                          // 3,200,000
    unsigned short* xb  = (unsigned short*)(edgedata + N_EDGES);  // 6,400,000 u16
    unsigned short* w1b = xb + (size_t)N_NODES * D;       // 81,920 u16
    unsigned short* w2b = w1b + NUM_RELS * D * D;         // 81,920 u16
    unsigned short* tbuf = w2b + NUM_RELS * D * D;        // RPC * 6,400,000 u16

    const size_t fixedB = (size_t)((char*)tbuf - (char*)d_ws);
    const size_t chunkB = (size_t)N_NODES * D * 2;        // 12.8 MB per relation
    int RPC = 1;
    if (ws_size >= fixedB + 10 * chunkB) RPC = 10;        // 128 MB t-chunk: L3-resident
    else if (ws_size >= fixedB + 5 * chunkB) RPC = 5;
    else if (ws_size >= fixedB + 2 * chunkB) RPC = 2;
    int NC = NUM_RELS / RPC;

    hipMemsetAsync(deg, 0, N_NODES * sizeof(int), stream);
    hipMemsetAsync(gsum, 0, 64 * sizeof(float), stream);

    // CSR by dst (multi-block scan) + weight conversion
    deg_count<<<N_EDGES / 256, 256, 0, stream>>>(dst, deg);
    scan_bsum<<<SCAN_B, 256, 0, stream>>>(deg, bsum);
    scan_bbase<<<1, 512, 0, stream>>>(bsum, bbase, off);
    scan_final<<<SCAN_B, 256, 0, stream>>>(deg, bbase, off, cur);
    scatter_edges<<<N_EDGES / 256, 256, 0, stream>>>(src, dst, etype, cur, edgedata);
    wconv_kernel<<<NUM_RELS, 256, 0, stream>>>(W1, w1b);
    wconv_kernel<<<NUM_RELS, 256, 0, stream>>>(W2, w2b);

    const int N4 = N_NODES * D / 4;
    dim3 tgrid((N_NODES / 16 + 3) / 4, RPC);

    // layer 1: final gather pass emits relu'd bf16 xb directly
    f2b_kernel<<<(N4 + 255) / 256, 256, 0, stream>>>(h, xb, N4, 0);
    for (int c = 0; c < NC; ++c) {
        transform_mfma<<<tgrid, 256, 0, stream>>>(xb, w1b, c * RPC, tbuf);
        int last = (c == NC - 1);
        gather_agg<<<8192, 256, 0, stream>>>(tbuf, edgedata, off, agg1, xb,
                                             c * RPC, RPC, c > 0, last ? 1 : 0);
    }
    // layer 2: writes out_h2 fp32
    for (int c = 0; c < NC; ++c) {
        transform_mfma<<<tgrid, 256, 0, stream>>>(xb, w2b, c * RPC, tbuf);
        gather_agg<<<8192, 256, 0, stream>>>(tbuf, edgedata, off, out_h2, nullptr,
                                             c * RPC, RPC, c > 0, 2);
    }

    // readout
    colsum_kernel<<<512, 256, 0, stream>>>(out_h2, gsum, N_NODES);
    mlp_kernel<<<1, 64, 0, stream>>>(gsum, A1w, A1b, A2w, A2b,
                                     out_a, 1.0f / (float)N_NODES);
}